// Round 1
// baseline (998.772 us; speedup 1.0000x reference)
//
#include <hip/hip_runtime.h>
#include <hip/hip_bf16.h>

// Problem constants (from reference setup_inputs)
#define M_TOK 8192
#define N_OUT 4096
#define K_IN  4096

typedef __attribute__((ext_vector_type(8))) __bf16 bf16x8;
typedef __attribute__((ext_vector_type(4))) float f32x4;

__device__ __forceinline__ unsigned short f2bf(float f) {
    return __builtin_bit_cast(unsigned short, (__bf16)f);
}

// ---------------------------------------------------------------------------
// Kernel 0: zero the reduction accumulators (ws is poisoned 0xAA each launch)
// ---------------------------------------------------------------------------
__global__ void init_sums_kernel(float* sums) {
    sums[0] = 0.0f;  // dense_sq
    sums[1] = 0.0f;  // sparse_sq
}

// ---------------------------------------------------------------------------
// Kernel 1: soft-threshold 2:4 sparsify along K, write bf16 W_s, reduce sums.
// One thread per group of 4 contiguous weights.
// ---------------------------------------------------------------------------
__global__ __launch_bounds__(256) void sparsify_kernel(
        const float* __restrict__ w,
        unsigned short* __restrict__ wsb,
        float* __restrict__ sums,
        int ngroups) {
    int gid = blockIdx.x * blockDim.x + threadIdx.x;
    float dsq = 0.0f, ssq = 0.0f;
    if (gid < ngroups) {
        const float4 g = ((const float4*)w)[gid];
        float a0 = fabsf(g.x), a1 = fabsf(g.y), a2 = fabsf(g.z), a3 = fabsf(g.w);
        // second-smallest of 4 = third-largest = soft threshold t
        float lo1 = fminf(a0, a1), hi1 = fmaxf(a0, a1);
        float lo2 = fminf(a2, a3), hi2 = fmaxf(a2, a3);
        float t = fminf(fmaxf(lo1, lo2), fminf(hi1, hi2));
        float s0 = (a0 > t) ? copysignf(a0 - t, g.x) : 0.0f;
        float s1 = (a1 > t) ? copysignf(a1 - t, g.y) : 0.0f;
        float s2 = (a2 > t) ? copysignf(a2 - t, g.z) : 0.0f;
        float s3 = (a3 > t) ? copysignf(a3 - t, g.w) : 0.0f;
        dsq = g.x * g.x + g.y * g.y + g.z * g.z + g.w * g.w;
        ssq = s0 * s0 + s1 * s1 + s2 * s2 + s3 * s3;
        ushort4 o;
        o.x = f2bf(s0); o.y = f2bf(s1); o.z = f2bf(s2); o.w = f2bf(s3);
        ((ushort4*)wsb)[gid] = o;
    }
    // wave64 shuffle reduce, then one atomic per block per sum
    for (int off = 32; off > 0; off >>= 1) {
        dsq += __shfl_down(dsq, off);
        ssq += __shfl_down(ssq, off);
    }
    __shared__ float sd[4], ss[4];
    int lane = threadIdx.x & 63, wv = threadIdx.x >> 6;
    if (lane == 0) { sd[wv] = dsq; ss[wv] = ssq; }
    __syncthreads();
    if (threadIdx.x == 0) {
        atomicAdd(&sums[0], sd[0] + sd[1] + sd[2] + sd[3]);
        atomicAdd(&sums[1], ss[0] + ss[1] + ss[2] + ss[3]);
    }
}

// ---------------------------------------------------------------------------
// Kernel 2: scale = clip(sqrt(dense_sq / max(sparse_sq,1e-12)), 0.1, 10)
// ---------------------------------------------------------------------------
__global__ void scale_kernel(float* sums) {
    float d = sums[0];
    float s = fmaxf(sums[1], 1e-12f);
    float sc = sqrtf(d / s);
    sums[2] = fminf(fmaxf(sc, 0.1f), 10.0f);
}

// ---------------------------------------------------------------------------
// Kernel 3: x fp32 -> bf16 (vectorized float4 -> ushort4)
// ---------------------------------------------------------------------------
__global__ __launch_bounds__(256) void convx_kernel(
        const float* __restrict__ x,
        unsigned short* __restrict__ xb,
        int n4) {
    int i = blockIdx.x * blockDim.x + threadIdx.x;
    if (i < n4) {
        float4 v = ((const float4*)x)[i];
        ushort4 o;
        o.x = f2bf(v.x); o.y = f2bf(v.y); o.z = f2bf(v.z); o.w = f2bf(v.w);
        ((ushort4*)xb)[i] = o;
    }
}

// ---------------------------------------------------------------------------
// Kernel 4: C[M][N] = scale * (A[M][K] @ B[N][K]^T) + bias[N]
// 128x128 block tile, BK=32, 4 waves, each wave 64x64 (4x4 of 16x16x32 MFMA).
// global_load_lds width-16 staging (m97 structure).
// ---------------------------------------------------------------------------
#define BM 128
#define BN 128
#define BK 32

__global__ __launch_bounds__(256) void gemm_bt_kernel(
        const unsigned short* __restrict__ A,   // x bf16 [M][K]
        const unsigned short* __restrict__ B,   // ws bf16 [N][K]
        const float* __restrict__ bias,         // [N]
        const float* __restrict__ sums,         // sums[2] = scale
        float* __restrict__ C,                  // [M][N]
        int M, int N, int K) {
    __shared__ __align__(16) unsigned short lA[BM * BK];
    __shared__ __align__(16) unsigned short lB[BN * BK];

    const int tid  = threadIdx.x;
    const int lane = tid & 63;
    const int wv   = tid >> 6;       // wave 0..3
    const int wm   = wv >> 1;        // wave row 0..1
    const int wn   = wv & 1;         // wave col 0..1
    const int quad = lane >> 4;      // 0..3
    const int l16  = lane & 15;

    const int m0 = blockIdx.y * BM;
    const int n0 = blockIdx.x * BN;

    f32x4 acc[4][4] = {};

    // Staging: 512 16B-chunks per tile; chunk c -> row c>>2, col (c&3)*8.
    // Wave-uniform LDS base + lane*16 (global_load_lds constraint).
    const int c0 = tid;         // chunks 0..255
    const int c1 = tid + 256;   // chunks 256..511
    unsigned short* lA0 = &lA[(wv * 64) * 8];
    unsigned short* lA1 = &lA[(256 + wv * 64) * 8];
    unsigned short* lB0 = &lB[(wv * 64) * 8];
    unsigned short* lB1 = &lB[(256 + wv * 64) * 8];

    const unsigned short* gA0 = &A[(size_t)(m0 + (c0 >> 2)) * K + (c0 & 3) * 8];
    const unsigned short* gA1 = &A[(size_t)(m0 + (c1 >> 2)) * K + (c1 & 3) * 8];
    const unsigned short* gB0 = &B[(size_t)(n0 + (c0 >> 2)) * K + (c0 & 3) * 8];
    const unsigned short* gB1 = &B[(size_t)(n0 + (c1 >> 2)) * K + (c1 & 3) * 8];

    for (int k0 = 0; k0 < K; k0 += BK) {
        __builtin_amdgcn_global_load_lds(
            (const __attribute__((address_space(1))) void*)gA0,
            (__attribute__((address_space(3))) void*)lA0, 16, 0, 0);
        __builtin_amdgcn_global_load_lds(
            (const __attribute__((address_space(1))) void*)gA1,
            (__attribute__((address_space(3))) void*)lA1, 16, 0, 0);
        __builtin_amdgcn_global_load_lds(
            (const __attribute__((address_space(1))) void*)gB0,
            (__attribute__((address_space(3))) void*)lB0, 16, 0, 0);
        __builtin_amdgcn_global_load_lds(
            (const __attribute__((address_space(1))) void*)gB1,
            (__attribute__((address_space(3))) void*)lB1, 16, 0, 0);
        gA0 += BK; gA1 += BK; gB0 += BK; gB1 += BK;

        asm volatile("s_waitcnt vmcnt(0)" ::: "memory");
        __syncthreads();

        bf16x8 af[4], bfr[4];
#pragma unroll
        for (int i = 0; i < 4; i++) {
            // A operand layout: m = lane&15, k = quad*8 + j (8 contiguous bf16)
            af[i]  = *(const bf16x8*)&lA[(wm * 64 + i * 16 + l16) * BK + quad * 8];
            bfr[i] = *(const bf16x8*)&lB[(wn * 64 + i * 16 + l16) * BK + quad * 8];
        }
#pragma unroll
        for (int i = 0; i < 4; i++)
#pragma unroll
            for (int j = 0; j < 4; j++)
                acc[i][j] = __builtin_amdgcn_mfma_f32_16x16x32_bf16(
                    af[i], bfr[j], acc[i][j], 0, 0, 0);

        __syncthreads();
    }

    const float scale = sums[2];
    // C/D layout: col = lane&15 (N dim), row = quad*4 + reg (M dim)
#pragma unroll
    for (int j = 0; j < 4; j++) {
        const int col = n0 + wn * 64 + j * 16 + l16;
        const float bv = bias[col];
#pragma unroll
        for (int i = 0; i < 4; i++) {
#pragma unroll
            for (int r = 0; r < 4; r++) {
                const int row = m0 + wm * 64 + i * 16 + quad * 4 + r;
                C[(size_t)row * N + col] = scale * acc[i][j][r] + bv;
            }
        }
    }
}

// ---------------------------------------------------------------------------
// Launch
// ---------------------------------------------------------------------------
extern "C" void kernel_launch(void* const* d_in, const int* in_sizes, int n_in,
                              void* d_out, int out_size, void* d_ws, size_t ws_size,
                              hipStream_t stream) {
    const float* x      = (const float*)d_in[0];   // [8192][4096]
    const float* weight = (const float*)d_in[1];   // [4096][4096]
    const float* bias   = (const float*)d_in[2];   // [4096]
    float* out          = (float*)d_out;           // [8192][4096]

    // Workspace layout
    char* ws = (char*)d_ws;
    float* sums          = (float*)ws;                               // 3 floats
    unsigned short* wsb  = (unsigned short*)(ws + 256);              // 32 MB bf16 W_s
    unsigned short* xb   = (unsigned short*)(ws + 256 + (size_t)N_OUT * K_IN * 2); // 64 MB bf16 x

    // 0) zero reduction cells
    init_sums_kernel<<<1, 1, 0, stream>>>(sums);

    // 1) sparsify + reduce
    const int ngroups = N_OUT * K_IN / 4;  // 4,194,304
    sparsify_kernel<<<ngroups / 256, 256, 0, stream>>>(weight, wsb, sums, ngroups);

    // 2) scale
    scale_kernel<<<1, 1, 0, stream>>>(sums);

    // 3) x -> bf16
    const int n4 = M_TOK * K_IN / 4;       // 8,388,608
    convx_kernel<<<n4 / 256, 256, 0, stream>>>(x, xb, n4);

    // 4) GEMM + epilogue
    dim3 grid(N_OUT / BN, M_TOK / BM);     // (32, 64)
    gemm_bt_kernel<<<grid, 256, 0, stream>>>(xb, wsb, bias, sums, out,
                                             M_TOK, N_OUT, K_IN);
}

// Round 2
// 591.880 us; speedup vs baseline: 1.6875x; 1.6875x over previous
//
#include <hip/hip_runtime.h>
#include <hip/hip_bf16.h>

// Problem constants (from reference setup_inputs)
#define M_TOK 8192
#define N_OUT 4096
#define K_IN  4096

#define SPARSIFY_BLOCKS 2048

typedef __attribute__((ext_vector_type(8))) __bf16 bf16x8;
typedef __attribute__((ext_vector_type(4))) float f32x4;

__device__ __forceinline__ unsigned short f2bf(float f) {
    return __builtin_bit_cast(unsigned short, (__bf16)f);
}

// ---------------------------------------------------------------------------
// Kernel 1: soft-threshold 2:4 sparsify along K, write bf16 W_s.
// Grid-stride, 2048 blocks; per-block partial sums written to pd/ps (NO atomics
// — same-address atomicAdd across 16k blocks serialized at ~25ns each = 420us).
// ---------------------------------------------------------------------------
__global__ __launch_bounds__(256) void sparsify_kernel(
        const float* __restrict__ w,
        unsigned short* __restrict__ wsb,
        float* __restrict__ pd,     // [SPARSIFY_BLOCKS] partial dense_sq
        float* __restrict__ ps,     // [SPARSIFY_BLOCKS] partial sparse_sq
        int ngroups) {
    const int stride = gridDim.x * blockDim.x;
    float dsq = 0.0f, ssq = 0.0f;
    for (int gid = blockIdx.x * blockDim.x + threadIdx.x; gid < ngroups;
         gid += stride) {
        const float4 g = ((const float4*)w)[gid];
        float a0 = fabsf(g.x), a1 = fabsf(g.y), a2 = fabsf(g.z), a3 = fabsf(g.w);
        // second-smallest of 4 = third-largest = soft threshold t
        float lo1 = fminf(a0, a1), hi1 = fmaxf(a0, a1);
        float lo2 = fminf(a2, a3), hi2 = fmaxf(a2, a3);
        float t = fminf(fmaxf(lo1, lo2), fminf(hi1, hi2));
        float s0 = (a0 > t) ? copysignf(a0 - t, g.x) : 0.0f;
        float s1 = (a1 > t) ? copysignf(a1 - t, g.y) : 0.0f;
        float s2 = (a2 > t) ? copysignf(a2 - t, g.z) : 0.0f;
        float s3 = (a3 > t) ? copysignf(a3 - t, g.w) : 0.0f;
        dsq += g.x * g.x + g.y * g.y + g.z * g.z + g.w * g.w;
        ssq += s0 * s0 + s1 * s1 + s2 * s2 + s3 * s3;
        ushort4 o;
        o.x = f2bf(s0); o.y = f2bf(s1); o.z = f2bf(s2); o.w = f2bf(s3);
        ((ushort4*)wsb)[gid] = o;
    }
    // wave64 shuffle reduce, then one LDS slot per wave, one write per block
    for (int off = 32; off > 0; off >>= 1) {
        dsq += __shfl_down(dsq, off);
        ssq += __shfl_down(ssq, off);
    }
    __shared__ float sd[4], ss[4];
    int lane = threadIdx.x & 63, wv = threadIdx.x >> 6;
    if (lane == 0) { sd[wv] = dsq; ss[wv] = ssq; }
    __syncthreads();
    if (threadIdx.x == 0) {
        pd[blockIdx.x] = sd[0] + sd[1] + sd[2] + sd[3];
        ps[blockIdx.x] = ss[0] + ss[1] + ss[2] + ss[3];
    }
}

// ---------------------------------------------------------------------------
// Kernel 2: reduce 2048 partials, scale = clip(sqrt(d / max(s,1e-12)), .1, 10)
// Single 256-thread block.
// ---------------------------------------------------------------------------
__global__ __launch_bounds__(256) void scale_kernel(
        const float* __restrict__ pd,
        const float* __restrict__ ps,
        float* __restrict__ sums) {
    float d = 0.0f, s = 0.0f;
#pragma unroll
    for (int k = 0; k < SPARSIFY_BLOCKS / 256; k++) {
        d += pd[threadIdx.x + k * 256];
        s += ps[threadIdx.x + k * 256];
    }
    for (int off = 32; off > 0; off >>= 1) {
        d += __shfl_down(d, off);
        s += __shfl_down(s, off);
    }
    __shared__ float sd[4], ss[4];
    int lane = threadIdx.x & 63, wv = threadIdx.x >> 6;
    if (lane == 0) { sd[wv] = d; ss[wv] = s; }
    __syncthreads();
    if (threadIdx.x == 0) {
        float dt = sd[0] + sd[1] + sd[2] + sd[3];
        float st = fmaxf(ss[0] + ss[1] + ss[2] + ss[3], 1e-12f);
        float sc = sqrtf(dt / st);
        sums[2] = fminf(fmaxf(sc, 0.1f), 10.0f);
    }
}

// ---------------------------------------------------------------------------
// Kernel 3: x fp32 -> bf16 (vectorized float4 -> ushort4)
// ---------------------------------------------------------------------------
__global__ __launch_bounds__(256) void convx_kernel(
        const float* __restrict__ x,
        unsigned short* __restrict__ xb,
        int n4) {
    int i = blockIdx.x * blockDim.x + threadIdx.x;
    if (i < n4) {
        float4 v = ((const float4*)x)[i];
        ushort4 o;
        o.x = f2bf(v.x); o.y = f2bf(v.y); o.z = f2bf(v.z); o.w = f2bf(v.w);
        ((ushort4*)xb)[i] = o;
    }
}

// ---------------------------------------------------------------------------
// Kernel 4: C[M][N] = scale * (A[M][K] @ B[N][K]^T) + bias[N]
// 128x128 block tile, BK=32, 4 waves, each wave 64x64 (4x4 of 16x16x32 MFMA).
// global_load_lds width-16 staging (m97 structure).
// ---------------------------------------------------------------------------
#define BM 128
#define BN 128
#define BK 32

__global__ __launch_bounds__(256) void gemm_bt_kernel(
        const unsigned short* __restrict__ A,   // x bf16 [M][K]
        const unsigned short* __restrict__ B,   // ws bf16 [N][K]
        const float* __restrict__ bias,         // [N]
        const float* __restrict__ sums,         // sums[2] = scale
        float* __restrict__ C,                  // [M][N]
        int M, int N, int K) {
    __shared__ __align__(16) unsigned short lA[BM * BK];
    __shared__ __align__(16) unsigned short lB[BN * BK];

    const int tid  = threadIdx.x;
    const int lane = tid & 63;
    const int wv   = tid >> 6;       // wave 0..3
    const int wm   = wv >> 1;        // wave row 0..1
    const int wn   = wv & 1;         // wave col 0..1
    const int quad = lane >> 4;      // 0..3
    const int l16  = lane & 15;

    const int m0 = blockIdx.y * BM;
    const int n0 = blockIdx.x * BN;

    f32x4 acc[4][4] = {};

    // Staging: 512 16B-chunks per tile; chunk c -> row c>>2, col (c&3)*8.
    // Wave-uniform LDS base + lane*16 (global_load_lds constraint).
    const int c0 = tid;         // chunks 0..255
    const int c1 = tid + 256;   // chunks 256..511
    unsigned short* lA0 = &lA[(wv * 64) * 8];
    unsigned short* lA1 = &lA[(256 + wv * 64) * 8];
    unsigned short* lB0 = &lB[(wv * 64) * 8];
    unsigned short* lB1 = &lB[(256 + wv * 64) * 8];

    const unsigned short* gA0 = &A[(size_t)(m0 + (c0 >> 2)) * K + (c0 & 3) * 8];
    const unsigned short* gA1 = &A[(size_t)(m0 + (c1 >> 2)) * K + (c1 & 3) * 8];
    const unsigned short* gB0 = &B[(size_t)(n0 + (c0 >> 2)) * K + (c0 & 3) * 8];
    const unsigned short* gB1 = &B[(size_t)(n0 + (c1 >> 2)) * K + (c1 & 3) * 8];

    for (int k0 = 0; k0 < K; k0 += BK) {
        __builtin_amdgcn_global_load_lds(
            (const __attribute__((address_space(1))) void*)gA0,
            (__attribute__((address_space(3))) void*)lA0, 16, 0, 0);
        __builtin_amdgcn_global_load_lds(
            (const __attribute__((address_space(1))) void*)gA1,
            (__attribute__((address_space(3))) void*)lA1, 16, 0, 0);
        __builtin_amdgcn_global_load_lds(
            (const __attribute__((address_space(1))) void*)gB0,
            (__attribute__((address_space(3))) void*)lB0, 16, 0, 0);
        __builtin_amdgcn_global_load_lds(
            (const __attribute__((address_space(1))) void*)gB1,
            (__attribute__((address_space(3))) void*)lB1, 16, 0, 0);
        gA0 += BK; gA1 += BK; gB0 += BK; gB1 += BK;

        asm volatile("s_waitcnt vmcnt(0)" ::: "memory");
        __syncthreads();

        bf16x8 af[4], bfr[4];
#pragma unroll
        for (int i = 0; i < 4; i++) {
            // A operand layout: m = lane&15, k = quad*8 + j (8 contiguous bf16)
            af[i]  = *(const bf16x8*)&lA[(wm * 64 + i * 16 + l16) * BK + quad * 8];
            bfr[i] = *(const bf16x8*)&lB[(wn * 64 + i * 16 + l16) * BK + quad * 8];
        }
#pragma unroll
        for (int i = 0; i < 4; i++)
#pragma unroll
            for (int j = 0; j < 4; j++)
                acc[i][j] = __builtin_amdgcn_mfma_f32_16x16x32_bf16(
                    af[i], bfr[j], acc[i][j], 0, 0, 0);

        __syncthreads();
    }

    const float scale = sums[2];
    // C/D layout: col = lane&15 (N dim), row = quad*4 + reg (M dim)
#pragma unroll
    for (int j = 0; j < 4; j++) {
        const int col = n0 + wn * 64 + j * 16 + l16;
        const float bv = bias[col];
#pragma unroll
        for (int i = 0; i < 4; i++) {
#pragma unroll
            for (int r = 0; r < 4; r++) {
                const int row = m0 + wm * 64 + i * 16 + quad * 4 + r;
                C[(size_t)row * N + col] = scale * acc[i][j][r] + bv;
            }
        }
    }
}

// ---------------------------------------------------------------------------
// Launch
// ---------------------------------------------------------------------------
extern "C" void kernel_launch(void* const* d_in, const int* in_sizes, int n_in,
                              void* d_out, int out_size, void* d_ws, size_t ws_size,
                              hipStream_t stream) {
    const float* x      = (const float*)d_in[0];   // [8192][4096]
    const float* weight = (const float*)d_in[1];   // [4096][4096]
    const float* bias   = (const float*)d_in[2];   // [4096]
    float* out          = (float*)d_out;           // [8192][4096]

    // Workspace layout
    char* ws = (char*)d_ws;
    float* sums         = (float*)ws;                         // 3 floats @ 0
    float* pd           = (float*)(ws + 1024);                // 2048 floats
    float* psm          = (float*)(ws + 1024 + 4 * SPARSIFY_BLOCKS);
    unsigned short* wsb = (unsigned short*)(ws + 32768);      // 32 MB bf16 W_s
    unsigned short* xb  = (unsigned short*)(ws + 32768 + (size_t)N_OUT * K_IN * 2); // 64 MB bf16 x

    // 1) sparsify + per-block partials (no atomics)
    const int ngroups = N_OUT * K_IN / 4;  // 4,194,304
    sparsify_kernel<<<SPARSIFY_BLOCKS, 256, 0, stream>>>(weight, wsb, pd, psm, ngroups);

    // 2) reduce partials + scale
    scale_kernel<<<1, 256, 0, stream>>>(pd, psm, sums);

    // 3) x -> bf16
    const int n4 = M_TOK * K_IN / 4;       // 8,388,608
    convx_kernel<<<n4 / 256, 256, 0, stream>>>(x, xb, n4);

    // 4) GEMM + epilogue
    dim3 grid(N_OUT / BN, M_TOK / BM);     // (32, 64)
    gemm_bt_kernel<<<grid, 256, 0, stream>>>(xb, wsb, bias, sums, out,
                                             M_TOK, N_OUT, K_IN);
}